// Round 21
// baseline (2842.875 us; speedup 1.0000x reference)
//
#include <hip/hip_runtime.h>
#include <hip/hip_bf16.h>

typedef __hip_bfloat16 hbf16;
using bf16x8 = __attribute__((ext_vector_type(8))) __bf16;
using f32x4 = __attribute__((ext_vector_type(4))) float;

// GPT-2 small: L=12 H=12 D=768 V=50257 T=1024 B=2, HD=64
constexpr int Lc = 12, Hc = 12, Dc = 768, Vc = 50257, Tc = 1024, Bc = 2, HDc = 64;
constexpr int Mc = Bc * Tc;  // 2048 rows
constexpr int Vpad = 50304;  // 393*128, zero-padded vocab

// transposed-weight slot sizes (elements)
constexpr size_t SZ_Q = (size_t)3 * Dc * Dc;   // [2304][768]
constexpr size_t SZ_P = (size_t)Dc * Dc;       // [768][768]
constexpr size_t SZ_F = (size_t)4 * Dc * Dc;   // [3072][768]
constexpr size_t SZ_FP = (size_t)4 * Dc * Dc;  // [768][3072]
constexpr size_t SZL = SZ_Q + SZ_P + SZ_F + SZ_FP;
constexpr int NPART = Bc * Hc * 8 * 2;  // 384 split partials
constexpr int NCNT = Bc * Hc * 8;       // 192 merge tickets per layer

#define GLD16(gp, lp)                                               \
    __builtin_amdgcn_global_load_lds(                               \
        (__attribute__((address_space(1))) void*)(void*)(gp),       \
        (__attribute__((address_space(3))) void*)(void*)(lp), 16, 0, 0)

// ---------------- embedding: h = wte[x] + wpe[t] (f32) ----------------
__global__ void embed_kernel(const int* __restrict__ x, const float* __restrict__ wte,
                             const float* __restrict__ wpe, float* __restrict__ h) {
    int i = blockIdx.x * blockDim.x + threadIdx.x;
    if (i >= Mc * Dc) return;
    int m = i / Dc, d = i - m * Dc;
    int t = m % Tc;
    int tok = x[m];
    h[i] = wte[(size_t)tok * Dc + d] + wpe[(size_t)t * Dc + d];
}

// ---------------- layernorm: one wave per row, shuffle reduce, f32 in -> bf16 out --
__global__ __launch_bounds__(256) void ln_kernel(const float* __restrict__ x,
                                                 const float* __restrict__ w,
                                                 const float* __restrict__ b,
                                                 hbf16* __restrict__ out) {
    int wv = threadIdx.x >> 6, lane = threadIdx.x & 63;
    int row = blockIdx.x * 4 + wv;
    const float4* xr = (const float4*)(x + (size_t)row * Dc);
    float4 v[3];
    float s = 0.f, sq = 0.f;
#pragma unroll
    for (int i = 0; i < 3; i++) {
        v[i] = xr[i * 64 + lane];
        s += v[i].x + v[i].y + v[i].z + v[i].w;
        sq += v[i].x * v[i].x + v[i].y * v[i].y + v[i].z * v[i].z + v[i].w * v[i].w;
    }
#pragma unroll
    for (int o = 32; o > 0; o >>= 1) {
        s += __shfl_xor(s, o, 64);
        sq += __shfl_xor(sq, o, 64);
    }
    float mean = s * (1.f / Dc);
    float var = sq * (1.f / Dc) - mean * mean;
    float rstd = rsqrtf(var + 1e-5f);
#pragma unroll
    for (int i = 0; i < 3; i++) {
        int c = (i * 64 + lane) * 4;
        float4 wv4 = *(const float4*)(w + c);
        float4 bv4 = *(const float4*)(b + c);
        float r0 = (v[i].x - mean) * rstd * wv4.x + bv4.x;
        float r1 = (v[i].y - mean) * rstd * wv4.y + bv4.y;
        float r2 = (v[i].z - mean) * rstd * wv4.z + bv4.z;
        float r3 = (v[i].w - mean) * rstd * wv4.w + bv4.w;
        __bf16 q0 = (__bf16)r0, q1 = (__bf16)r1, q2 = (__bf16)r2, q3 = (__bf16)r3;
        ushort4 u;
        u.x = *(unsigned short*)&q0; u.y = *(unsigned short*)&q1;
        u.z = *(unsigned short*)&q2; u.w = *(unsigned short*)&q3;
        *(ushort4*)(out + (size_t)row * Dc + c) = u;
    }
}

// ---------------- weight transpose, grid (6912, nlayers) ----------------
__global__ __launch_bounds__(256) void transpose4_kernel(
    const float* __restrict__ s0, const float* __restrict__ s1,
    const float* __restrict__ s2, const float* __restrict__ s3,
    hbf16* __restrict__ d0, hbf16* __restrict__ d1,
    hbf16* __restrict__ d2, hbf16* __restrict__ d3) {
    int id = blockIdx.x;
    size_t lz = blockIdx.y;
    int bx, by, K, N;
    const float* W;
    hbf16* Wt;
    if (id < 1728)      { int t = id;        bx = t % 72; by = t / 72; K = 768;  N = 2304; W = s0 + lz * SZ_Q;  Wt = d0 + lz * SZL; }
    else if (id < 2304) { int t = id - 1728; bx = t % 24; by = t / 24; K = 768;  N = 768;  W = s1 + lz * SZ_P;  Wt = d1 + lz * SZL; }
    else if (id < 4608) { int t = id - 2304; bx = t % 96; by = t / 96; K = 768;  N = 3072; W = s2 + lz * SZ_F;  Wt = d2 + lz * SZL; }
    else                { int t = id - 4608; bx = t % 24; by = t / 24; K = 3072; N = 768;  W = s3 + lz * SZ_FP; Wt = d3 + lz * SZL; }

    __shared__ float tile[32][33];
    int n0 = bx * 32, k0 = by * 32;
    int tx = threadIdx.x & 31, ty = threadIdx.x >> 5;  // 32x8
#pragma unroll
    for (int i = 0; i < 4; i++) {
        int r = ty + i * 8;
        tile[r][tx] = W[(size_t)(k0 + r) * N + n0 + tx];
    }
    __syncthreads();
#pragma unroll
    for (int i = 0; i < 4; i++) {
        int r = ty + i * 8;
        Wt[(size_t)(n0 + r) * K + k0 + tx] = __float2bfloat16(tile[tx][r]);
    }
}

// ---------------- wte f32 [V][D] -> bf16 [Vpad][D] (zero pad) ----------------
__global__ void convert_wte(const float* __restrict__ wte, hbf16* __restrict__ out) {
    size_t i4 = ((size_t)blockIdx.x * 256 + threadIdx.x) * 4;
    if (i4 >= (size_t)Vpad * Dc) return;
    if (i4 < (size_t)Vc * Dc) {
#pragma unroll
        for (int j = 0; j < 4; j++) out[i4 + j] = __float2bfloat16(wte[i4 + j]);
    } else {
#pragma unroll
        for (int j = 0; j < 4; j++) out[i4 + j] = __float2bfloat16(0.f);
    }
}

// ---------------- MFMA GEMM 64xBN, BK=64, dbuf + counted vmcnt (R18 form) ---------
// EPI: 0 = +bias, 1 = +bias +f32 residual, 2 = +bias + tanh-GELU
template <int EPI, bool OUTBF, int BN>
__global__ __launch_bounds__(256) void mm_kernel(const hbf16* __restrict__ A,
                                                 const hbf16* __restrict__ Bt,
                                                 const float* __restrict__ bias,
                                                 const float* __restrict__ resid,
                                                 void* __restrict__ Cout,
                                                 int M, int N, int K) {
    constexpr int NF = BN / 32;   // n-frags per wave
    constexpr int NBI = BN / 32;  // B stage issues (32 rows each)
    __shared__ __bf16 As[2][64 * 64];   // 2 x 8 KB
    __shared__ __bf16 Bs[2][BN * 64];   // 2 x 16/8 KB
    int tid = threadIdx.x;
    int l = tid & 63, w = tid >> 6;
    int wr = w >> 1, wc = w & 1;

    // XCD swizzle: hw dispatch order is x-fastest; chunk per XCD, m fastest.
    int gx = gridDim.x, gy = gridDim.y;
    int nwg = gx * gy;
    int hwlin = blockIdx.y * gx + blockIdx.x;
    int wk = (hwlin & 7) * (nwg >> 3) + (hwlin >> 3);
    int m0 = (wk % gy) * 64;
    int n0 = (wk / gy) * BN;

    // staging: 32 rows/issue; row = j*32 + (tid>>3), 16B slot sc = tid&7
    int sr = tid >> 3, sc = tid & 7;
    int scs = (sc ^ (sr & 7)) * 8;
    const hbf16* pA[2];
#pragma unroll
    for (int j = 0; j < 2; j++) pA[j] = A + (size_t)(m0 + j * 32 + sr) * K + scs;
    const hbf16* pB[NBI];
#pragma unroll
    for (int j = 0; j < NBI; j++) pB[j] = Bt + (size_t)(n0 + j * 32 + sr) * K + scs;

    auto stage = [&](int bi, int ko) {
#pragma unroll
        for (int j = 0; j < 2; j++) GLD16(pA[j] + ko, &As[bi][j * 2048 + tid * 8]);
#pragma unroll
        for (int j = 0; j < NBI; j++) GLD16(pB[j] + ko, &Bs[bi][j * 2048 + tid * 8]);
    };

    int lr = l & 15, lg = l >> 4;
    int aoff[2][2], boff[2][NF];
#pragma unroll
    for (int kk = 0; kk < 2; kk++) {
        int ks = ((kk * 4 + lg) ^ (lr & 7)) * 8;
#pragma unroll
        for (int m = 0; m < 2; m++) aoff[kk][m] = (wr * 32 + m * 16 + lr) * 64 + ks;
#pragma unroll
        for (int n = 0; n < NF; n++) boff[kk][n] = (wc * (BN / 2) + n * 16 + lr) * 64 + ks;
    }

    f32x4 acc[2][NF] = {};
    int nk = K / 64;

    stage(0, 0);
    for (int t = 0; t < nk; ++t) {
        int cur = t & 1;
        if (t + 1 < nk) {
            stage(cur ^ 1, (t + 1) * 64);
            if constexpr (BN == 128)
                asm volatile("s_waitcnt vmcnt(6)" ::: "memory");
            else
                asm volatile("s_waitcnt vmcnt(4)" ::: "memory");
        } else {
            asm volatile("s_waitcnt vmcnt(0)" ::: "memory");
        }
        __builtin_amdgcn_sched_barrier(0);
        __builtin_amdgcn_s_barrier();
        __builtin_amdgcn_sched_barrier(0);
#pragma unroll
        for (int kk = 0; kk < 2; kk++) {
            bf16x8 af[2], bfr[NF];
#pragma unroll
            for (int m = 0; m < 2; m++) af[m] = *(const bf16x8*)&As[cur][aoff[kk][m]];
#pragma unroll
            for (int n = 0; n < NF; n++) bfr[n] = *(const bf16x8*)&Bs[cur][boff[kk][n]];
#pragma unroll
            for (int m = 0; m < 2; m++)
#pragma unroll
                for (int n = 0; n < NF; n++)
                    acc[m][n] = __builtin_amdgcn_mfma_f32_16x16x32_bf16(af[m], bfr[n], acc[m][n], 0, 0, 0);
        }
        __builtin_amdgcn_s_barrier();
    }

#pragma unroll
    for (int n = 0; n < NF; n++) {
        int col = n0 + wc * (BN / 2) + n * 16 + lr;
        bool cok = col < N;
        float bv = (bias && cok) ? bias[col] : 0.f;
#pragma unroll
        for (int m = 0; m < 2; m++) {
#pragma unroll
            for (int r = 0; r < 4; r++) {
                int row = m0 + wr * 32 + m * 16 + lg * 4 + r;
                if (!cok) continue;
                float v = acc[m][n][r] + bv;
                if (EPI == 1) v += resid[(size_t)row * N + col];
                if (EPI == 2) {
                    float x3 = v * v * v;
                    v = 0.5f * v * (1.f + tanhf(0.7978845608028654f * (v + 0.044715f * x3)));
                }
                if (OUTBF)
                    ((hbf16*)Cout)[(size_t)row * N + col] = __float2bfloat16(v);
                else
                    ((float*)Cout)[(size_t)row * N + col] = v;
            }
        }
    }
}

// ---------------- MFMA GEMM 256x128, 512 threads, BK=64 single-buffer + setprio ---
__global__ __launch_bounds__(512) void mm2_kernel(const hbf16* __restrict__ A,
                                                  const hbf16* __restrict__ Bt,
                                                  float* __restrict__ Cout,
                                                  int M, int N, int K) {
    __shared__ __bf16 As[256 * 64];  // 32 KB
    __shared__ __bf16 Bs[128 * 64];  // 16 KB
    int tid = threadIdx.x;
    int l = tid & 63, w = tid >> 6;
    int wr = w >> 1, wc = w & 1;

    int gx = gridDim.x, gy = gridDim.y;  // gy = 8
    int nwg = gx * gy;
    int hwlin = blockIdx.y * gx + blockIdx.x;
    int wk = (hwlin & 7) * (nwg >> 3) + (hwlin >> 3);
    int m0 = (wk & 7) * 256;
    int n0 = (wk >> 3) * 128;

    int sr = tid >> 3, sc = tid & 7;
    int scs = (sc ^ (sr & 7)) * 8;
    const hbf16* pA[4];
    __bf16* lA[4];
#pragma unroll
    for (int j = 0; j < 4; j++) {
        pA[j] = A + (size_t)(m0 + j * 64 + sr) * K + scs;
        lA[j] = As + j * 4096 + tid * 8;
    }
    const hbf16* pB[2];
    __bf16* lB[2];
#pragma unroll
    for (int j = 0; j < 2; j++) {
        pB[j] = Bt + (size_t)(n0 + j * 64 + sr) * K + scs;
        lB[j] = Bs + j * 4096 + tid * 8;
    }

    int lr = l & 15, lg = l >> 4;
    int aoff[2][4], boff[2][4];
#pragma unroll
    for (int kk = 0; kk < 2; kk++) {
        int ks = ((kk * 4 + lg) ^ (lr & 7)) * 8;
#pragma unroll
        for (int m = 0; m < 4; m++) aoff[kk][m] = (wr * 64 + m * 16 + lr) * 64 + ks;
#pragma unroll
        for (int n = 0; n < 4; n++) boff[kk][n] = (wc * 64 + n * 16 + lr) * 64 + ks;
    }

    f32x4 acc[4][4] = {};

    for (int k0 = 0; k0 < K; k0 += 64) {
#pragma unroll
        for (int j = 0; j < 4; j++) {
            GLD16(pA[j], lA[j]);
            pA[j] += 64;
        }
#pragma unroll
        for (int j = 0; j < 2; j++) {
            GLD16(pB[j], lB[j]);
            pB[j] += 64;
        }
        __syncthreads();
        __builtin_amdgcn_s_setprio(1);
#pragma unroll
        for (int kk = 0; kk < 2; kk++) {
            bf16x8 af[4], bfr[4];
#pragma unroll
            for (int m = 0; m < 4; m++) af[m] = *(const bf16x8*)&As[aoff[kk][m]];
#pragma unroll
            for (int n = 0; n < 4; n++) bfr[n] = *(const bf16x8*)&Bs[boff[kk][n]];
#pragma unroll
            for (int m = 0; m < 4; m++)
#pragma unroll
                for (int n = 0; n < 4; n++)
                    acc[m][n] = __builtin_amdgcn_mfma_f32_16x16x32_bf16(af[m], bfr[n], acc[m][n], 0, 0, 0);
        }
        __builtin_amdgcn_s_setprio(0);
        __syncthreads();
    }

#pragma unroll
    for (int n = 0; n < 4; n++) {
        int col = n0 + wc * 64 + n * 16 + lr;
        if (col >= N) continue;
#pragma unroll
        for (int m = 0; m < 4; m++) {
#pragma unroll
            for (int r = 0; r < 4; r++) {
                int row = m0 + wr * 64 + m * 16 + lg * 4 + r;
                Cout[(size_t)row * N + col] = acc[m][n][r];
            }
        }
    }
}

// ---------------- MFMA flash attention, split-K with inlined ticket merge ---------
// grid (24, H, B). s<16: heavy split halves (write partials; second arriver merges).
// s>=16: light blocks write y directly.
__global__ __launch_bounds__(256) void fattn_kernel(const hbf16* __restrict__ qkv,
                                                    hbf16* __restrict__ y,
                                                    float* __restrict__ part_O,
                                                    float* __restrict__ part_m,
                                                    float* __restrict__ part_l,
                                                    int* __restrict__ cnt) {
    int s = blockIdx.x;
    int h = blockIdx.y, b = blockIdx.z;
    int qt, jlo, jhi, half = 0;
    bool partial;
    if (s < 16) {
        qt = 8 + (s >> 1);
        half = s & 1;
        int mid = (qt + 1) >> 1;
        jlo = half ? mid : 0;
        jhi = half ? qt : mid - 1;
        partial = true;
    } else {
        qt = s - 16;
        jlo = 0;
        jhi = qt;
        partial = false;
    }
    int q0 = qt * 64;
    int tid = threadIdx.x;
    int l = tid & 63, w = tid >> 6;
    int li = l & 15, lg = l >> 4;
    constexpr int RS = 3 * Dc;
    constexpr int PST = 72;
    constexpr int VST = 72;
    constexpr float SCL = 0.125f * 1.44269504f;  // 1/sqrt(64) * log2(e)
    constexpr float THR = 11.5f;                 // defer-max threshold (log2 domain)

    __shared__ __bf16 K_lds[2][64 * 64];   // 2 x 8 KB, swizzled 16B slots
    __shared__ __bf16 Vt[2][64 * VST];     // 2 x 9 KB
    __shared__ __bf16 P_lds[4][16 * PST];  // 9 KB  (layout [q_local][j])
    __shared__ int ticket;

    bf16x8 qf[2];
    {
        const hbf16* qp = qkv + (size_t)(b * Tc + q0 + w * 16 + li) * RS + h * HDc + lg * 8;
        qf[0] = *(const bf16x8*)qp;
        qf[1] = *(const bf16x8*)(qp + 32);
    }

    int krow0 = tid >> 3, krow1 = 32 + (tid >> 3);
    int ks8 = tid & 7;
    int kc0 = (ks8 ^ (krow0 & 7)) * 8;
    int kc1 = (ks8 ^ (krow1 & 7)) * 8;
    const hbf16* kbase = qkv + (size_t)(b * Tc) * RS + Dc + h * HDc;

    int jp = (tid >> 3) * 2;
    int db = (tid & 7) * 8;
    const hbf16* vbase = qkv + (size_t)(b * Tc) * RS + 2 * Dc + h * HDc;

    int koff[2][4];
#pragma unroll
    for (int ks = 0; ks < 2; ks++)
#pragma unroll
        for (int n = 0; n < 4; n++)
            koff[ks][n] = (n * 16 + li) * 64 + (((ks * 4 + lg) ^ (li & 7)) * 8);

    f32x4 acc_o[4] = {};
    float m_run = -1e30f, l_run = 0.f;  // scalar: lane owns q = w*16+li

    int j0p = jlo * 64;
    bf16x8 vr0, vr1;
    {
        const hbf16* vp = vbase + (size_t)(j0p + jp) * RS + db;
        vr0 = *(const bf16x8*)vp;
        vr1 = *(const bf16x8*)(vp + RS);
        GLD16(kbase + (size_t)(j0p + krow0) * RS + kc0, &K_lds[0][tid * 8]);
        GLD16(kbase + (size_t)(j0p + krow1) * RS + kc1, &K_lds[0][2048 + tid * 8]);
    }
#pragma unroll
    for (int i = 0; i < 8; i++) {
        __bf16 a0 = vr0[i], a1 = vr1[i];
        unsigned u = (unsigned)*(unsigned short*)&a0 | ((unsigned)*(unsigned short*)&a1 << 16);
        *(unsigned*)&Vt[0][(db + i) * VST + jp] = u;
    }

    int cur = 0;
    for (int jt = jlo; jt <= jhi; jt++) {
        int jn0 = (jt < jhi) ? (jt + 1) * 64 : j0p;  // dummy wrap keeps vmcnt invariant

        asm volatile("s_waitcnt lgkmcnt(0)" ::: "memory");
        __builtin_amdgcn_s_barrier();

        {
            const hbf16* vp = vbase + (size_t)(jn0 + jp) * RS + db;
            vr0 = *(const bf16x8*)vp;
            vr1 = *(const bf16x8*)(vp + RS);
            GLD16(kbase + (size_t)(jn0 + krow0) * RS + kc0, &K_lds[cur ^ 1][tid * 8]);
            GLD16(kbase + (size_t)(jn0 + krow1) * RS + kc1, &K_lds[cur ^ 1][2048 + tid * 8]);
        }

        asm volatile("s_waitcnt vmcnt(4)" ::: "memory");
        __builtin_amdgcn_sched_barrier(0);

        // ---- S = K Q^T (swapped): s[n][r] = S[j=n*16+lg*4+r][q=li] ----
        f32x4 sv[4] = {};
#pragma unroll
        for (int ks = 0; ks < 2; ks++)
#pragma unroll
            for (int n = 0; n < 4; n++) {
                bf16x8 kf = *(const bf16x8*)&K_lds[cur][koff[ks][n]];
                sv[n] = __builtin_amdgcn_mfma_f32_16x16x32_bf16(kf, qf[ks], sv[n], 0, 0, 0);
            }
#pragma unroll
        for (int n = 0; n < 4; n++)
#pragma unroll
            for (int r = 0; r < 4; r++) sv[n][r] *= SCL;

        if (jt == qt) {
            int qloc = w * 16 + li;
#pragma unroll
            for (int n = 0; n < 4; n++)
#pragma unroll
                for (int r = 0; r < 4; r++)
                    if (n * 16 + lg * 4 + r > qloc) sv[n][r] = -1e30f;
        }

        // ---- online softmax: all 16 values belong to q = w*16+li ----
        float mx = -1e30f;
#pragma unroll
        for (int n = 0; n < 4; n++)
#pragma unroll
            for (int r = 0; r < 4; r++) mx = fmaxf(mx, sv[n][r]);
        mx = fmaxf(mx, __shfl_xor(mx, 16, 64));
        mx = fmaxf(mx, __shfl_xor(mx, 32, 64));

        bool dfr = __all(mx - m_run <= THR);
        float sclq = 1.f;
        if (!dfr) {
            float mnew = fmaxf(m_run, mx);
            sclq = exp2f(m_run - mnew);
            m_run = mnew;
        }
        float rs = 0.f;
#pragma unroll
        for (int n = 0; n < 4; n++)
#pragma unroll
            for (int r = 0; r < 4; r++) {
                float pv = exp2f(sv[n][r] - m_run);
                sv[n][r] = pv;
                rs += pv;
            }
        rs += __shfl_xor(rs, 16, 64);
        rs += __shfl_xor(rs, 32, 64);
        l_run = (dfr ? l_run : l_run * sclq) + rs;

        // ---- P -> LDS [q=li][j], packed pairs ----
#pragma unroll
        for (int n = 0; n < 4; n++)
#pragma unroll
            for (int r = 0; r < 4; r += 2) {
                __bf16 b0 = (__bf16)sv[n][r], b1 = (__bf16)sv[n][r + 1];
                unsigned u = (unsigned)*(unsigned short*)&b0 |
                             ((unsigned)*(unsigned short*)&b1 << 16);
                *(unsigned*)&P_lds[w][li * PST + n * 16 + lg * 4 + r] = u;
            }
        bf16x8 pa0 = *(const bf16x8*)&P_lds[w][li * PST + lg * 8];
        bf16x8 pa1 = *(const bf16x8*)&P_lds[w][li * PST + 32 + lg * 8];

        if (!dfr) {
#pragma unroll
            for (int r = 0; r < 4; r++) {
                float sr_ = __shfl(sclq, (l & 48) | (lg * 4 + r), 64);
#pragma unroll
                for (int n2 = 0; n2 < 4; n2++) acc_o[n2][r] *= sr_;
            }
        }

        // ---- PV from Vt[cur] ----
#pragma unroll
        for (int n2 = 0; n2 < 4; n2++) {
            bf16x8 vf0 = *(const bf16x8*)&Vt[cur][(n2 * 16 + li) * VST + lg * 8];
            bf16x8 vf1 = *(const bf16x8*)&Vt[cur][(n2 * 16 + li) * VST + 32 + lg * 8];
            acc_o[n2] = __builtin_amdgcn_mfma_f32_16x16x32_bf16(pa0, vf0, acc_o[n2], 0, 0, 0);
            acc_o[n2] = __builtin_amdgcn_mfma_f32_16x16x32_bf16(pa1, vf1, acc_o[n2], 0, 0, 0);
        }

        // ---- write V(jt+1) regs -> Vt[cur^1] ----
#pragma unroll
        for (int i = 0; i < 8; i++) {
            __bf16 a0 = vr0[i], a1 = vr1[i];
            unsigned u = (unsigned)*(unsigned short*)&a0 | ((unsigned)*(unsigned short*)&a1 << 16);
            *(unsigned*)&Vt[cur ^ 1][(db + i) * VST + jp] = u;
        }
        cur ^= 1;
    }

    if (partial) {
        int bh = b * Hc + h;
        int pi = bh * 8 + (qt - 8);
        int p0 = pi * 2, pme = p0 + half;
#pragma unroll
        for (int r = 0; r < 4; r++) {
            int lrow = w * 16 + lg * 4 + r;
#pragma unroll
            for (int n2 = 0; n2 < 4; n2++)
                part_O[(size_t)pme * 4096 + lrow * 64 + n2 * 16 + li] = acc_o[n2][r];
        }
        if (lg == 0) {
            part_m[pme * 64 + w * 16 + li] = m_run;
            part_l[pme * 64 + w * 16 + li] = l_run;
        }
        // ticket: second arriver merges both halves into y
        __syncthreads();      // all threads' stores issued & drained
        __threadfence();      // device-visible before the atomic
        if (tid == 0) ticket = atomicAdd(&cnt[pi], 1);
        __syncthreads();
        if (ticket == 1) {
            __threadfence();  // acquire: other half's partials visible
            int p1 = p0 + 1;
#pragma unroll 4
            for (int rr = 0; rr < 16; rr++) {
                int lrow = w * 16 + rr;
                float m0v = part_m[p0 * 64 + lrow], m1v = part_m[p1 * 64 + lrow];
                float l0v = part_l[p0 * 64 + lrow], l1v = part_l[p1 * 64 + lrow];
                float mm_ = fmaxf(m0v, m1v);
                float a0 = exp2f(m0v - mm_), a1 = exp2f(m1v - mm_);
                float lsum = l0v * a0 + l1v * a1;
                float o0 = part_O[(size_t)p0 * 4096 + lrow * 64 + l];
                float o1 = part_O[(size_t)p1 * 4096 + lrow * 64 + l];
                float o = (o0 * a0 + o1 * a1) / lsum;
                y[((size_t)b * Tc + q0 + lrow) * Dc + h * HDc + l] = __float2bfloat16(o);
            }
        }
    } else {
#pragma unroll
        for (int r = 0; r < 4; r++) {
            float lv = __shfl(l_run, (l & 48) | (lg * 4 + r), 64);
            float rcp = 1.f / lv;
            int row = q0 + w * 16 + lg * 4 + r;
#pragma unroll
            for (int n2 = 0; n2 < 4; n2++)
                y[(size_t)(b * Tc + row) * Dc + h * HDc + n2 * 16 + li] =
                    __float2bfloat16(acc_o[n2][r] * rcp);
        }
    }
}

extern "C" void kernel_launch(void* const* d_in, const int* in_sizes, int n_in,
                              void* d_out, int out_size, void* d_ws, size_t ws_size,
                              hipStream_t stream) {
    const int* x = (const int*)d_in[0];
    const float* wte = (const float*)d_in[1];
    const float* wpe = (const float*)d_in[2];
    const float* ln1w = (const float*)d_in[3];
    const float* ln1b = (const float*)d_in[4];
    const float* qkvw = (const float*)d_in[5];
    const float* qkvb = (const float*)d_in[6];
    const float* projw = (const float*)d_in[7];
    const float* projb = (const float*)d_in[8];
    const float* ln2w = (const float*)d_in[9];
    const float* ln2b = (const float*)d_in[10];
    const float* fcw = (const float*)d_in[11];
    const float* fcb = (const float*)d_in[12];
    const float* fcpw = (const float*)d_in[13];
    const float* fcpb = (const float*)d_in[14];
    const float* lnfw = (const float*)d_in[15];
    const float* lnfb = (const float*)d_in[16];

    char* p = (char*)d_ws;
    float* h = (float*)p;      p += (size_t)Mc * Dc * 4;      // f32 [M][D]
    hbf16* qkv = (hbf16*)p;    p += (size_t)Mc * 3 * Dc * 2;  // bf16 [M][3D]
    hbf16* a = (hbf16*)p;      p += (size_t)Mc * Dc * 2;      // bf16 [M][D]
    hbf16* y = (hbf16*)p;      p += (size_t)Mc * Dc * 2;      // bf16 [M][D]
    hbf16* mlp = (hbf16*)p;    p += (size_t)Mc * 4 * Dc * 2;  // bf16 [M][4D]
    hbf16* wte_b = (hbf16*)p;  p += (size_t)Vpad * Dc * 2;    // [50304][768]
    float* part_O = (float*)p; p += (size_t)NPART * 4096 * 4; // 6.3 MB
    float* part_m = (float*)p; p += (size_t)NPART * 64 * 4;
    float* part_l = (float*)p; p += (size_t)NPART * 64 * 4;
    int* cnt = (int*)p;        p += (size_t)Lc * NCNT * 4;    // merge tickets
    hbf16* wtr = (hbf16*)p;                                   // transposed weights
    size_t used = (size_t)((char*)wtr - (char*)d_ws);
    bool all_mode = (ws_size - used) >= (size_t)Lc * SZL * 2;

    hipMemsetAsync(cnt, 0, (size_t)Lc * NCNT * 4, stream);
    embed_kernel<<<(Mc * Dc + 255) / 256, 256, 0, stream>>>(x, wte, wpe, h);
    convert_wte<<<((size_t)Vpad * Dc / 4 + 255) / 256, 256, 0, stream>>>(wte, wte_b);

    if (all_mode) {
        transpose4_kernel<<<dim3(6912, Lc), 256, 0, stream>>>(
            qkvw, projw, fcw, fcpw,
            wtr, wtr + SZ_Q, wtr + SZ_Q + SZ_P, wtr + SZ_Q + SZ_P + SZ_F);
    }

    for (int l = 0; l < Lc; l++) {
        hbf16* base = wtr + (all_mode ? (size_t)l * SZL : 0);
        hbf16* wq_t = base;
        hbf16* wp_t = base + SZ_Q;
        hbf16* wf_t = base + SZ_Q + SZ_P;
        hbf16* wfp_t = base + SZ_Q + SZ_P + SZ_F;
        if (!all_mode) {
            transpose4_kernel<<<dim3(6912, 1), 256, 0, stream>>>(
                qkvw + (size_t)l * SZ_Q, projw + (size_t)l * SZ_P,
                fcw + (size_t)l * SZ_F, fcpw + (size_t)l * SZ_FP,
                wq_t, wp_t, wf_t, wfp_t);
        }

        ln_kernel<<<Mc / 4, 256, 0, stream>>>(h, ln1w + (size_t)l * Dc, ln1b + (size_t)l * Dc, a);
        mm_kernel<0, true, 128><<<dim3(3 * Dc / 128, Mc / 64), 256, 0, stream>>>(
            a, wq_t, qkvb + (size_t)l * 3 * Dc, nullptr, qkv, Mc, 3 * Dc, Dc);
        fattn_kernel<<<dim3(24, Hc, Bc), 256, 0, stream>>>(
            qkv, y, part_O, part_m, part_l, cnt + l * NCNT);
        mm_kernel<1, false, 64><<<dim3(Dc / 64, Mc / 64), 256, 0, stream>>>(
            y, wp_t, projb + (size_t)l * Dc, h, h, Mc, Dc, Dc);
        ln_kernel<<<Mc / 4, 256, 0, stream>>>(h, ln2w + (size_t)l * Dc, ln2b + (size_t)l * Dc, a);
        mm_kernel<2, true, 128><<<dim3(4 * Dc / 128, Mc / 64), 256, 0, stream>>>(
            a, wf_t, fcb + (size_t)l * 4 * Dc, nullptr, mlp, Mc, 4 * Dc, Dc);
        mm_kernel<1, false, 64><<<dim3(Dc / 64, Mc / 64), 256, 0, stream>>>(
            mlp, wfp_t, fcpb + (size_t)l * Dc, h, h, Mc, Dc, 4 * Dc);
    }

    ln_kernel<<<Mc / 4, 256, 0, stream>>>(h, lnfw, lnfb, a);
    mm2_kernel<<<dim3(Vpad / 128, Mc / 256), 512, 0, stream>>>(
        a, wte_b, (float*)d_out, Mc, Vc, Dc);
}

// Round 22
// 2031.966 us; speedup vs baseline: 1.3991x; 1.3991x over previous
//
#include <hip/hip_runtime.h>
#include <hip/hip_bf16.h>

typedef __hip_bfloat16 hbf16;
using bf16x8 = __attribute__((ext_vector_type(8))) __bf16;
using f32x4 = __attribute__((ext_vector_type(4))) float;

// GPT-2 small: L=12 H=12 D=768 V=50257 T=1024 B=2, HD=64
constexpr int Lc = 12, Hc = 12, Dc = 768, Vc = 50257, Tc = 1024, Bc = 2, HDc = 64;
constexpr int Mc = Bc * Tc;  // 2048 rows
constexpr int Vpad = 50304;  // 393*128, zero-padded vocab

// transposed-weight slot sizes (elements)
constexpr size_t SZ_Q = (size_t)3 * Dc * Dc;   // [2304][768]
constexpr size_t SZ_P = (size_t)Dc * Dc;       // [768][768]
constexpr size_t SZ_F = (size_t)4 * Dc * Dc;   // [3072][768]
constexpr size_t SZ_FP = (size_t)4 * Dc * Dc;  // [768][3072]
constexpr size_t SZL = SZ_Q + SZ_P + SZ_F + SZ_FP;
constexpr int NPART = Bc * Hc * 8 * 2;  // 384 split partials

#define GLD16(gp, lp)                                               \
    __builtin_amdgcn_global_load_lds(                               \
        (__attribute__((address_space(1))) void*)(void*)(gp),       \
        (__attribute__((address_space(3))) void*)(void*)(lp), 16, 0, 0)

// ---------------- embedding: h = wte[x] + wpe[t] (f32) ----------------
__global__ void embed_kernel(const int* __restrict__ x, const float* __restrict__ wte,
                             const float* __restrict__ wpe, float* __restrict__ h) {
    int i = blockIdx.x * blockDim.x + threadIdx.x;
    if (i >= Mc * Dc) return;
    int m = i / Dc, d = i - m * Dc;
    int t = m % Tc;
    int tok = x[m];
    h[i] = wte[(size_t)tok * Dc + d] + wpe[(size_t)t * Dc + d];
}

// ---------------- layernorm: one wave per row, shuffle reduce, f32 in -> bf16 out --
__global__ __launch_bounds__(256) void ln_kernel(const float* __restrict__ x,
                                                 const float* __restrict__ w,
                                                 const float* __restrict__ b,
                                                 hbf16* __restrict__ out) {
    int wv = threadIdx.x >> 6, lane = threadIdx.x & 63;
    int row = blockIdx.x * 4 + wv;
    const float4* xr = (const float4*)(x + (size_t)row * Dc);
    float4 v[3];
    float s = 0.f, sq = 0.f;
#pragma unroll
    for (int i = 0; i < 3; i++) {
        v[i] = xr[i * 64 + lane];
        s += v[i].x + v[i].y + v[i].z + v[i].w;
        sq += v[i].x * v[i].x + v[i].y * v[i].y + v[i].z * v[i].z + v[i].w * v[i].w;
    }
#pragma unroll
    for (int o = 32; o > 0; o >>= 1) {
        s += __shfl_xor(s, o, 64);
        sq += __shfl_xor(sq, o, 64);
    }
    float mean = s * (1.f / Dc);
    float var = sq * (1.f / Dc) - mean * mean;
    float rstd = rsqrtf(var + 1e-5f);
#pragma unroll
    for (int i = 0; i < 3; i++) {
        int c = (i * 64 + lane) * 4;
        float4 wv4 = *(const float4*)(w + c);
        float4 bv4 = *(const float4*)(b + c);
        float r0 = (v[i].x - mean) * rstd * wv4.x + bv4.x;
        float r1 = (v[i].y - mean) * rstd * wv4.y + bv4.y;
        float r2 = (v[i].z - mean) * rstd * wv4.z + bv4.z;
        float r3 = (v[i].w - mean) * rstd * wv4.w + bv4.w;
        __bf16 q0 = (__bf16)r0, q1 = (__bf16)r1, q2 = (__bf16)r2, q3 = (__bf16)r3;
        ushort4 u;
        u.x = *(unsigned short*)&q0; u.y = *(unsigned short*)&q1;
        u.z = *(unsigned short*)&q2; u.w = *(unsigned short*)&q3;
        *(ushort4*)(out + (size_t)row * Dc + c) = u;
    }
}

// ---------------- weight transpose, grid (6912, nlayers) ----------------
__global__ __launch_bounds__(256) void transpose4_kernel(
    const float* __restrict__ s0, const float* __restrict__ s1,
    const float* __restrict__ s2, const float* __restrict__ s3,
    hbf16* __restrict__ d0, hbf16* __restrict__ d1,
    hbf16* __restrict__ d2, hbf16* __restrict__ d3) {
    int id = blockIdx.x;
    size_t lz = blockIdx.y;
    int bx, by, K, N;
    const float* W;
    hbf16* Wt;
    if (id < 1728)      { int t = id;        bx = t % 72; by = t / 72; K = 768;  N = 2304; W = s0 + lz * SZ_Q;  Wt = d0 + lz * SZL; }
    else if (id < 2304) { int t = id - 1728; bx = t % 24; by = t / 24; K = 768;  N = 768;  W = s1 + lz * SZ_P;  Wt = d1 + lz * SZL; }
    else if (id < 4608) { int t = id - 2304; bx = t % 96; by = t / 96; K = 768;  N = 3072; W = s2 + lz * SZ_F;  Wt = d2 + lz * SZL; }
    else                { int t = id - 4608; bx = t % 24; by = t / 24; K = 3072; N = 768;  W = s3 + lz * SZ_FP; Wt = d3 + lz * SZL; }

    __shared__ float tile[32][33];
    int n0 = bx * 32, k0 = by * 32;
    int tx = threadIdx.x & 31, ty = threadIdx.x >> 5;  // 32x8
#pragma unroll
    for (int i = 0; i < 4; i++) {
        int r = ty + i * 8;
        tile[r][tx] = W[(size_t)(k0 + r) * N + n0 + tx];
    }
    __syncthreads();
#pragma unroll
    for (int i = 0; i < 4; i++) {
        int r = ty + i * 8;
        Wt[(size_t)(n0 + r) * K + k0 + tx] = __float2bfloat16(tile[tx][r]);
    }
}

// ---------------- wte f32 [V][D] -> bf16 [Vpad][D] (zero pad) ----------------
__global__ void convert_wte(const float* __restrict__ wte, hbf16* __restrict__ out) {
    size_t i4 = ((size_t)blockIdx.x * 256 + threadIdx.x) * 4;
    if (i4 >= (size_t)Vpad * Dc) return;
    if (i4 < (size_t)Vc * Dc) {
#pragma unroll
        for (int j = 0; j < 4; j++) out[i4 + j] = __float2bfloat16(wte[i4 + j]);
    } else {
#pragma unroll
        for (int j = 0; j < 4; j++) out[i4 + j] = __float2bfloat16(0.f);
    }
}

// ---------------- MFMA GEMM 64xBN, BK=64, dbuf + counted vmcnt (R18) ----------
// EPI: 0 = +bias, 1 = +bias +f32 residual, 2 = +bias + tanh-GELU
template <int EPI, bool OUTBF, int BN>
__global__ __launch_bounds__(256) void mm_kernel(const hbf16* __restrict__ A,
                                                 const hbf16* __restrict__ Bt,
                                                 const float* __restrict__ bias,
                                                 const float* __restrict__ resid,
                                                 void* __restrict__ Cout,
                                                 int M, int N, int K) {
    constexpr int NF = BN / 32;   // n-frags per wave
    constexpr int NBI = BN / 32;  // B stage issues (32 rows each)
    __shared__ __bf16 As[2][64 * 64];   // 2 x 8 KB
    __shared__ __bf16 Bs[2][BN * 64];   // 2 x 16/8 KB
    int tid = threadIdx.x;
    int l = tid & 63, w = tid >> 6;
    int wr = w >> 1, wc = w & 1;

    // XCD swizzle: hw dispatch order is x-fastest; chunk per XCD, m fastest.
    int gx = gridDim.x, gy = gridDim.y;
    int nwg = gx * gy;
    int hwlin = blockIdx.y * gx + blockIdx.x;
    int wk = (hwlin & 7) * (nwg >> 3) + (hwlin >> 3);
    int m0 = (wk % gy) * 64;
    int n0 = (wk / gy) * BN;

    // staging: 32 rows/issue; row = j*32 + (tid>>3), 16B slot sc = tid&7
    int sr = tid >> 3, sc = tid & 7;
    int scs = (sc ^ (sr & 7)) * 8;
    const hbf16* pA[2];
#pragma unroll
    for (int j = 0; j < 2; j++) pA[j] = A + (size_t)(m0 + j * 32 + sr) * K + scs;
    const hbf16* pB[NBI];
#pragma unroll
    for (int j = 0; j < NBI; j++) pB[j] = Bt + (size_t)(n0 + j * 32 + sr) * K + scs;

    auto stage = [&](int bi, int ko) {
#pragma unroll
        for (int j = 0; j < 2; j++) GLD16(pA[j] + ko, &As[bi][j * 2048 + tid * 8]);
#pragma unroll
        for (int j = 0; j < NBI; j++) GLD16(pB[j] + ko, &Bs[bi][j * 2048 + tid * 8]);
    };

    int lr = l & 15, lg = l >> 4;
    int aoff[2][2], boff[2][NF];
#pragma unroll
    for (int kk = 0; kk < 2; kk++) {
        int ks = ((kk * 4 + lg) ^ (lr & 7)) * 8;
#pragma unroll
        for (int m = 0; m < 2; m++) aoff[kk][m] = (wr * 32 + m * 16 + lr) * 64 + ks;
#pragma unroll
        for (int n = 0; n < NF; n++) boff[kk][n] = (wc * (BN / 2) + n * 16 + lr) * 64 + ks;
    }

    f32x4 acc[2][NF] = {};
    int nk = K / 64;

    stage(0, 0);
    for (int t = 0; t < nk; ++t) {
        int cur = t & 1;
        if (t + 1 < nk) {
            stage(cur ^ 1, (t + 1) * 64);
            if constexpr (BN == 128)
                asm volatile("s_waitcnt vmcnt(6)" ::: "memory");
            else
                asm volatile("s_waitcnt vmcnt(4)" ::: "memory");
        } else {
            asm volatile("s_waitcnt vmcnt(0)" ::: "memory");
        }
        __builtin_amdgcn_sched_barrier(0);
        __builtin_amdgcn_s_barrier();
        __builtin_amdgcn_sched_barrier(0);
#pragma unroll
        for (int kk = 0; kk < 2; kk++) {
            bf16x8 af[2], bfr[NF];
#pragma unroll
            for (int m = 0; m < 2; m++) af[m] = *(const bf16x8*)&As[cur][aoff[kk][m]];
#pragma unroll
            for (int n = 0; n < NF; n++) bfr[n] = *(const bf16x8*)&Bs[cur][boff[kk][n]];
#pragma unroll
            for (int m = 0; m < 2; m++)
#pragma unroll
                for (int n = 0; n < NF; n++)
                    acc[m][n] = __builtin_amdgcn_mfma_f32_16x16x32_bf16(af[m], bfr[n], acc[m][n], 0, 0, 0);
        }
        __builtin_amdgcn_s_barrier();
    }

#pragma unroll
    for (int n = 0; n < NF; n++) {
        int col = n0 + wc * (BN / 2) + n * 16 + lr;
        bool cok = col < N;
        float bv = (bias && cok) ? bias[col] : 0.f;
#pragma unroll
        for (int m = 0; m < 2; m++) {
#pragma unroll
            for (int r = 0; r < 4; r++) {
                int row = m0 + wr * 32 + m * 16 + lg * 4 + r;
                if (!cok) continue;
                float v = acc[m][n][r] + bv;
                if (EPI == 1) v += resid[(size_t)row * N + col];
                if (EPI == 2) {
                    float x3 = v * v * v;
                    v = 0.5f * v * (1.f + tanhf(0.7978845608028654f * (v + 0.044715f * x3)));
                }
                if (OUTBF)
                    ((hbf16*)Cout)[(size_t)row * N + col] = __float2bfloat16(v);
                else
                    ((float*)Cout)[(size_t)row * N + col] = v;
            }
        }
    }
}

// ---------------- MFMA GEMM 256x128, 512 threads, BK=64 single-buffer (R14) -------
__global__ __launch_bounds__(512) void mm2_kernel(const hbf16* __restrict__ A,
                                                  const hbf16* __restrict__ Bt,
                                                  float* __restrict__ Cout,
                                                  int M, int N, int K) {
    __shared__ __bf16 As[256 * 64];  // 32 KB
    __shared__ __bf16 Bs[128 * 64];  // 16 KB
    int tid = threadIdx.x;
    int l = tid & 63, w = tid >> 6;
    int wr = w >> 1, wc = w & 1;

    int gx = gridDim.x, gy = gridDim.y;  // gy = 8
    int nwg = gx * gy;
    int hwlin = blockIdx.y * gx + blockIdx.x;
    int wk = (hwlin & 7) * (nwg >> 3) + (hwlin >> 3);
    int m0 = (wk & 7) * 256;
    int n0 = (wk >> 3) * 128;

    int sr = tid >> 3, sc = tid & 7;
    int scs = (sc ^ (sr & 7)) * 8;
    const hbf16* pA[4];
    __bf16* lA[4];
#pragma unroll
    for (int j = 0; j < 4; j++) {
        pA[j] = A + (size_t)(m0 + j * 64 + sr) * K + scs;
        lA[j] = As + j * 4096 + tid * 8;
    }
    const hbf16* pB[2];
    __bf16* lB[2];
#pragma unroll
    for (int j = 0; j < 2; j++) {
        pB[j] = Bt + (size_t)(n0 + j * 64 + sr) * K + scs;
        lB[j] = Bs + j * 4096 + tid * 8;
    }

    int lr = l & 15, lg = l >> 4;
    int aoff[2][4], boff[2][4];
#pragma unroll
    for (int kk = 0; kk < 2; kk++) {
        int ks = ((kk * 4 + lg) ^ (lr & 7)) * 8;
#pragma unroll
        for (int m = 0; m < 4; m++) aoff[kk][m] = (wr * 64 + m * 16 + lr) * 64 + ks;
#pragma unroll
        for (int n = 0; n < 4; n++) boff[kk][n] = (wc * 64 + n * 16 + lr) * 64 + ks;
    }

    f32x4 acc[4][4] = {};

    for (int k0 = 0; k0 < K; k0 += 64) {
#pragma unroll
        for (int j = 0; j < 4; j++) {
            GLD16(pA[j], lA[j]);
            pA[j] += 64;
        }
#pragma unroll
        for (int j = 0; j < 2; j++) {
            GLD16(pB[j], lB[j]);
            pB[j] += 64;
        }
        __syncthreads();
#pragma unroll
        for (int kk = 0; kk < 2; kk++) {
            bf16x8 af[4], bfr[4];
#pragma unroll
            for (int m = 0; m < 4; m++) af[m] = *(const bf16x8*)&As[aoff[kk][m]];
#pragma unroll
            for (int n = 0; n < 4; n++) bfr[n] = *(const bf16x8*)&Bs[boff[kk][n]];
#pragma unroll
            for (int m = 0; m < 4; m++)
#pragma unroll
                for (int n = 0; n < 4; n++)
                    acc[m][n] = __builtin_amdgcn_mfma_f32_16x16x32_bf16(af[m], bfr[n], acc[m][n], 0, 0, 0);
        }
        __syncthreads();
    }

#pragma unroll
    for (int n = 0; n < 4; n++) {
        int col = n0 + wc * 64 + n * 16 + lr;
        if (col >= N) continue;
#pragma unroll
        for (int m = 0; m < 4; m++) {
#pragma unroll
            for (int r = 0; r < 4; r++) {
                int row = m0 + wr * 64 + m * 16 + lg * 4 + r;
                Cout[(size_t)row * N + col] = acc[m][n][r];
            }
        }
    }
}

// ---------------- MFMA flash attention, pipelined + swapped QK^T + split-K --------
__global__ __launch_bounds__(256) void fattn_kernel(const hbf16* __restrict__ qkv,
                                                    hbf16* __restrict__ y,
                                                    float* __restrict__ part_O,
                                                    float* __restrict__ part_m,
                                                    float* __restrict__ part_l) {
    int s = blockIdx.x;
    int h = blockIdx.y, b = blockIdx.z;
    int qt, jlo, jhi, half = 0;
    bool partial;
    if (s < 16) {
        qt = 8 + (s >> 1);
        half = s & 1;
        int mid = (qt + 1) >> 1;
        jlo = half ? mid : 0;
        jhi = half ? qt : mid - 1;
        partial = true;
    } else {
        qt = s - 16;
        jlo = 0;
        jhi = qt;
        partial = false;
    }
    int q0 = qt * 64;
    int tid = threadIdx.x;
    int l = tid & 63, w = tid >> 6;
    int li = l & 15, lg = l >> 4;
    constexpr int RS = 3 * Dc;
    constexpr int PST = 72;
    constexpr int VST = 72;
    constexpr float SCL = 0.125f * 1.44269504f;  // 1/sqrt(64) * log2(e)
    constexpr float THR = 11.5f;                 // defer-max threshold (log2 domain)

    __shared__ __bf16 K_lds[2][64 * 64];   // 2 x 8 KB, swizzled 16B slots
    __shared__ __bf16 Vt[2][64 * VST];     // 2 x 9 KB
    __shared__ __bf16 P_lds[4][16 * PST];  // 9 KB  (layout [q_local][j])

    bf16x8 qf[2];
    {
        const hbf16* qp = qkv + (size_t)(b * Tc + q0 + w * 16 + li) * RS + h * HDc + lg * 8;
        qf[0] = *(const bf16x8*)qp;
        qf[1] = *(const bf16x8*)(qp + 32);
    }

    int krow0 = tid >> 3, krow1 = 32 + (tid >> 3);
    int ks8 = tid & 7;
    int kc0 = (ks8 ^ (krow0 & 7)) * 8;
    int kc1 = (ks8 ^ (krow1 & 7)) * 8;
    const hbf16* kbase = qkv + (size_t)(b * Tc) * RS + Dc + h * HDc;

    int jp = (tid >> 3) * 2;
    int db = (tid & 7) * 8;
    const hbf16* vbase = qkv + (size_t)(b * Tc) * RS + 2 * Dc + h * HDc;

    int koff[2][4];
#pragma unroll
    for (int ks = 0; ks < 2; ks++)
#pragma unroll
        for (int n = 0; n < 4; n++)
            koff[ks][n] = (n * 16 + li) * 64 + (((ks * 4 + lg) ^ (li & 7)) * 8);

    f32x4 acc_o[4] = {};
    float m_run = -1e30f, l_run = 0.f;  // scalar: lane owns q = w*16+li

    int j0p = jlo * 64;
    bf16x8 vr0, vr1;
    {
        const hbf16* vp = vbase + (size_t)(j0p + jp) * RS + db;
        vr0 = *(const bf16x8*)vp;
        vr1 = *(const bf16x8*)(vp + RS);
        GLD16(kbase + (size_t)(j0p + krow0) * RS + kc0, &K_lds[0][tid * 8]);
        GLD16(kbase + (size_t)(j0p + krow1) * RS + kc1, &K_lds[0][2048 + tid * 8]);
    }
#pragma unroll
    for (int i = 0; i < 8; i++) {
        __bf16 a0 = vr0[i], a1 = vr1[i];
        unsigned u = (unsigned)*(unsigned short*)&a0 | ((unsigned)*(unsigned short*)&a1 << 16);
        *(unsigned*)&Vt[0][(db + i) * VST + jp] = u;
    }

    int cur = 0;
    for (int jt = jlo; jt <= jhi; jt++) {
        int jn0 = (jt < jhi) ? (jt + 1) * 64 : j0p;  // dummy wrap keeps vmcnt invariant

        asm volatile("s_waitcnt lgkmcnt(0)" ::: "memory");
        __builtin_amdgcn_s_barrier();

        {
            const hbf16* vp = vbase + (size_t)(jn0 + jp) * RS + db;
            vr0 = *(const bf16x8*)vp;
            vr1 = *(const bf16x8*)(vp + RS);
            GLD16(kbase + (size_t)(jn0 + krow0) * RS + kc0, &K_lds[cur ^ 1][tid * 8]);
            GLD16(kbase + (size_t)(jn0 + krow1) * RS + kc1, &K_lds[cur ^ 1][2048 + tid * 8]);
        }

        asm volatile("s_waitcnt vmcnt(4)" ::: "memory");
        __builtin_amdgcn_sched_barrier(0);

        // ---- S = K Q^T (swapped): s[n][r] = S[j=n*16+lg*4+r][q=li] ----
        f32x4 sv[4] = {};
#pragma unroll
        for (int ks = 0; ks < 2; ks++)
#pragma unroll
            for (int n = 0; n < 4; n++) {
                bf16x8 kf = *(const bf16x8*)&K_lds[cur][koff[ks][n]];
                sv[n] = __builtin_amdgcn_mfma_f32_16x16x32_bf16(kf, qf[ks], sv[n], 0, 0, 0);
            }
#pragma unroll
        for (int n = 0; n < 4; n++)
#pragma unroll
            for (int r = 0; r < 4; r++) sv[n][r] *= SCL;

        if (jt == qt) {
            int qloc = w * 16 + li;
#pragma unroll
            for (int n = 0; n < 4; n++)
#pragma unroll
                for (int r = 0; r < 4; r++)
                    if (n * 16 + lg * 4 + r > qloc) sv[n][r] = -1e30f;
        }

        // ---- online softmax: all 16 values belong to q = w*16+li ----
        float mx = -1e30f;
#pragma unroll
        for (int n = 0; n < 4; n++)
#pragma unroll
            for (int r = 0; r < 4; r++) mx = fmaxf(mx, sv[n][r]);
        mx = fmaxf(mx, __shfl_xor(mx, 16, 64));
        mx = fmaxf(mx, __shfl_xor(mx, 32, 64));

        bool dfr = __all(mx - m_run <= THR);
        float sclq = 1.f;
        if (!dfr) {
            float mnew = fmaxf(m_run, mx);
            sclq = exp2f(m_run - mnew);
            m_run = mnew;
        }
        float rs = 0.f;
#pragma unroll
        for (int n = 0; n < 4; n++)
#pragma unroll
            for (int r = 0; r < 4; r++) {
                float pv = exp2f(sv[n][r] - m_run);
                sv[n][r] = pv;
                rs += pv;
            }
        rs += __shfl_xor(rs, 16, 64);
        rs += __shfl_xor(rs, 32, 64);
        l_run = (dfr ? l_run : l_run * sclq) + rs;

        // ---- P -> LDS [q=li][j], packed pairs ----
#pragma unroll
        for (int n = 0; n < 4; n++)
#pragma unroll
            for (int r = 0; r < 4; r += 2) {
                __bf16 b0 = (__bf16)sv[n][r], b1 = (__bf16)sv[n][r + 1];
                unsigned u = (unsigned)*(unsigned short*)&b0 |
                             ((unsigned)*(unsigned short*)&b1 << 16);
                *(unsigned*)&P_lds[w][li * PST + n * 16 + lg * 4 + r] = u;
            }
        bf16x8 pa0 = *(const bf16x8*)&P_lds[w][li * PST + lg * 8];
        bf16x8 pa1 = *(const bf16x8*)&P_lds[w][li * PST + 32 + lg * 8];

        if (!dfr) {
#pragma unroll
            for (int r = 0; r < 4; r++) {
                float sr_ = __shfl(sclq, (l & 48) | (lg * 4 + r), 64);
#pragma unroll
                for (int n2 = 0; n2 < 4; n2++) acc_o[n2][r] *= sr_;
            }
        }

        // ---- PV from Vt[cur] ----
#pragma unroll
        for (int n2 = 0; n2 < 4; n2++) {
            bf16x8 vf0 = *(const bf16x8*)&Vt[cur][(n2 * 16 + li) * VST + lg * 8];
            bf16x8 vf1 = *(const bf16x8*)&Vt[cur][(n2 * 16 + li) * VST + 32 + lg * 8];
            acc_o[n2] = __builtin_amdgcn_mfma_f32_16x16x32_bf16(pa0, vf0, acc_o[n2], 0, 0, 0);
            acc_o[n2] = __builtin_amdgcn_mfma_f32_16x16x32_bf16(pa1, vf1, acc_o[n2], 0, 0, 0);
        }

        // ---- write V(jt+1) regs -> Vt[cur^1] ----
#pragma unroll
        for (int i = 0; i < 8; i++) {
            __bf16 a0 = vr0[i], a1 = vr1[i];
            unsigned u = (unsigned)*(unsigned short*)&a0 | ((unsigned)*(unsigned short*)&a1 << 16);
            *(unsigned*)&Vt[cur ^ 1][(db + i) * VST + jp] = u;
        }
        cur ^= 1;
    }

    if (partial) {
        int p = ((b * Hc + h) * 8 + (qt - 8)) * 2 + half;
#pragma unroll
        for (int r = 0; r < 4; r++) {
            int lrow = w * 16 + lg * 4 + r;
#pragma unroll
            for (int n2 = 0; n2 < 4; n2++)
                part_O[(size_t)p * 4096 + lrow * 64 + n2 * 16 + li] = acc_o[n2][r];
        }
        if (lg == 0) {
            part_m[p * 64 + w * 16 + li] = m_run;
            part_l[p * 64 + w * 16 + li] = l_run;
        }
    } else {
#pragma unroll
        for (int r = 0; r < 4; r++) {
            float lv = __shfl(l_run, (l & 48) | (lg * 4 + r), 64);
            float rcp = 1.f / lv;
            int row = q0 + w * 16 + lg * 4 + r;
#pragma unroll
            for (int n2 = 0; n2 < 4; n2++)
                y[(size_t)(b * Tc + row) * Dc + h * HDc + n2 * 16 + li] =
                    __float2bfloat16(acc_o[n2][r] * rcp);
        }
    }
}

// ---------------- merge split-K partials: one wave per q-row ----------------
__global__ __launch_bounds__(256) void fmerge_kernel(const float* __restrict__ part_O,
                                                     const float* __restrict__ part_m,
                                                     const float* __restrict__ part_l,
                                                     hbf16* __restrict__ y) {
    int gi = blockIdx.x * 4 + (threadIdx.x >> 6);
    int lane = threadIdx.x & 63;
    int row512 = gi & 511;
    int bh = gi >> 9;
    int b = bh / Hc, h = bh % Hc;
    int qt8 = row512 >> 6, lrow = row512 & 63;
    int p0 = (bh * 8 + qt8) * 2, p1 = p0 + 1;
    float m0 = part_m[p0 * 64 + lrow], m1 = part_m[p1 * 64 + lrow];
    float l0 = part_l[p0 * 64 + lrow], l1 = part_l[p1 * 64 + lrow];
    float m = fmaxf(m0, m1);
    float a0 = exp2f(m0 - m), a1 = exp2f(m1 - m);
    float lsum = l0 * a0 + l1 * a1;
    float o0 = part_O[(size_t)p0 * 4096 + lrow * 64 + lane];
    float o1 = part_O[(size_t)p1 * 4096 + lrow * 64 + lane];
    float o = (o0 * a0 + o1 * a1) / lsum;
    int q = (8 + qt8) * 64 + lrow;
    y[((size_t)b * Tc + q) * Dc + h * HDc + lane] = __float2bfloat16(o);
}

extern "C" void kernel_launch(void* const* d_in, const int* in_sizes, int n_in,
                              void* d_out, int out_size, void* d_ws, size_t ws_size,
                              hipStream_t stream) {
    const int* x = (const int*)d_in[0];
    const float* wte = (const float*)d_in[1];
    const float* wpe = (const float*)d_in[2];
    const float* ln1w = (const float*)d_in[3];
    const float* ln1b = (const float*)d_in[4];
    const float* qkvw = (const float*)d_in[5];
    const float* qkvb = (const float*)d_in[6];
    const float* projw = (const float*)d_in[7];
    const float* projb = (const float*)d_in[8];
    const float* ln2w = (const float*)d_in[9];
    const float* ln2b = (const float*)d_in[10];
    const float* fcw = (const float*)d_in[11];
    const float* fcb = (const float*)d_in[12];
    const float* fcpw = (const float*)d_in[13];
    const float* fcpb = (const float*)d_in[14];
    const float* lnfw = (const float*)d_in[15];
    const float* lnfb = (const float*)d_in[16];

    char* p = (char*)d_ws;
    float* h = (float*)p;      p += (size_t)Mc * Dc * 4;      // f32 [M][D]
    hbf16* qkv = (hbf16*)p;    p += (size_t)Mc * 3 * Dc * 2;  // bf16 [M][3D]
    hbf16* a = (hbf16*)p;      p += (size_t)Mc * Dc * 2;      // bf16 [M][D]
    hbf16* y = (hbf16*)p;      p += (size_t)Mc * Dc * 2;      // bf16 [M][D]
    hbf16* mlp = (hbf16*)p;    p += (size_t)Mc * 4 * Dc * 2;  // bf16 [M][4D]
    hbf16* wte_b = (hbf16*)p;  p += (size_t)Vpad * Dc * 2;    // [50304][768]
    float* part_O = (float*)p; p += (size_t)NPART * 4096 * 4; // 6.3 MB
    float* part_m = (float*)p; p += (size_t)NPART * 64 * 4;
    float* part_l = (float*)p; p += (size_t)NPART * 64 * 4;
    hbf16* wtr = (hbf16*)p;                                   // transposed weights
    size_t used = (size_t)((char*)wtr - (char*)d_ws);
    bool all_mode = (ws_size - used) >= (size_t)Lc * SZL * 2;

    embed_kernel<<<(Mc * Dc + 255) / 256, 256, 0, stream>>>(x, wte, wpe, h);
    convert_wte<<<((size_t)Vpad * Dc / 4 + 255) / 256, 256, 0, stream>>>(wte, wte_b);

    if (all_mode) {
        transpose4_kernel<<<dim3(6912, Lc), 256, 0, stream>>>(
            qkvw, projw, fcw, fcpw,
            wtr, wtr + SZ_Q, wtr + SZ_Q + SZ_P, wtr + SZ_Q + SZ_P + SZ_F);
    }

    for (int l = 0; l < Lc; l++) {
        hbf16* base = wtr + (all_mode ? (size_t)l * SZL : 0);
        hbf16* wq_t = base;
        hbf16* wp_t = base + SZ_Q;
        hbf16* wf_t = base + SZ_Q + SZ_P;
        hbf16* wfp_t = base + SZ_Q + SZ_P + SZ_F;
        if (!all_mode) {
            transpose4_kernel<<<dim3(6912, 1), 256, 0, stream>>>(
                qkvw + (size_t)l * SZ_Q, projw + (size_t)l * SZ_P,
                fcw + (size_t)l * SZ_F, fcpw + (size_t)l * SZ_FP,
                wq_t, wp_t, wf_t, wfp_t);
        }

        ln_kernel<<<Mc / 4, 256, 0, stream>>>(h, ln1w + (size_t)l * Dc, ln1b + (size_t)l * Dc, a);
        mm_kernel<0, true, 128><<<dim3(3 * Dc / 128, Mc / 64), 256, 0, stream>>>(
            a, wq_t, qkvb + (size_t)l * 3 * Dc, nullptr, qkv, Mc, 3 * Dc, Dc);
        fattn_kernel<<<dim3(24, Hc, Bc), 256, 0, stream>>>(qkv, y, part_O, part_m, part_l);
        fmerge_kernel<<<Bc * Hc * 512 / 4, 256, 0, stream>>>(part_O, part_m, part_l, y);
        mm_kernel<1, false, 64><<<dim3(Dc / 64, Mc / 64), 256, 0, stream>>>(
            y, wp_t, projb + (size_t)l * Dc, h, h, Mc, Dc, Dc);
        ln_kernel<<<Mc / 4, 256, 0, stream>>>(h, ln2w + (size_t)l * Dc, ln2b + (size_t)l * Dc, a);
        mm_kernel<2, true, 128><<<dim3(4 * Dc / 128, Mc / 64), 256, 0, stream>>>(
            a, wf_t, fcb + (size_t)l * 4 * Dc, nullptr, mlp, Mc, 4 * Dc, Dc);
        mm_kernel<1, false, 64><<<dim3(Dc / 64, Mc / 64), 256, 0, stream>>>(
            mlp, wfp_t, fcpb + (size_t)l * Dc, h, h, Mc, Dc, 4 * Dc);
    }

    ln_kernel<<<Mc / 4, 256, 0, stream>>>(h, lnfw, lnfb, a);
    mm2_kernel<<<dim3(Vpad / 128, Mc / 256), 512, 0, stream>>>(
        a, wte_b, (float*)d_out, Mc, Vc, Dc);
}